// Round 1
// baseline (1125.098 us; speedup 1.0000x reference)
//
#include <hip/hip_runtime.h>
#include <hip/hip_cooperative_groups.h>

namespace cg = cooperative_groups;

// N = 4,194,304 = NBLK * NTHR * ELEMS exactly.
constexpr int NBLK  = 256;   // 1 block per CU -> cheap cooperative residency
constexpr int NTHR  = 1024;  // 16 waves/block
constexpr int ELEMS = 16;    // per-thread oscillators held in registers
constexpr float DT  = 0.01f;

// Block-wide sum of two values, broadcast to all threads.
// red[] must be __shared__ float[32]. Safe to call repeatedly (entry barrier).
__device__ inline void block_sum2(float a, float b, float* red,
                                  float& oa, float& ob) {
  #pragma unroll
  for (int off = 32; off > 0; off >>= 1) {
    a += __shfl_down(a, off);
    b += __shfl_down(b, off);
  }
  const int lane = threadIdx.x & 63;
  const int wv   = threadIdx.x >> 6;   // 0..15
  __syncthreads();                     // protect red[] from previous call's reads
  if (lane == 0) { red[wv] = a; red[16 + wv] = b; }
  __syncthreads();
  float sa = 0.f, sb = 0.f;
  #pragma unroll
  for (int w = 0; w < 16; ++w) { sa += red[w]; sb += red[16 + w]; }
  oa = sa; ob = sb;
}

__global__ __launch_bounds__(NTHR, 4)
void sl_persistent(const float* __restrict__ zr0,
                   const float* __restrict__ zi0,
                   const float* __restrict__ om_in,
                   const float* __restrict__ mu_p,
                   const float* __restrict__ cp_p,
                   const int*   __restrict__ st_p,
                   float* __restrict__ out,
                   float2* __restrict__ pbuf,   // [2*NBLK] mean partials (dbuf) + [NBLK] amp partials
                   int n) {
  cg::grid_group grid = cg::this_grid();
  __shared__ float red[32];

  const int tid = blockIdx.x * NTHR + threadIdx.x;
  const int T   = NBLK * NTHR;
  const float mu   = *mu_p;
  const float cpl  = *cp_p;
  const int   steps = *st_p;
  const float invN = 1.0f / (float)n;

  // ---- load state into registers, compute step-0 partial sums ----
  float zr[ELEMS], zi[ELEMS], om[ELEMS];
  float sr = 0.f, si = 0.f;
  #pragma unroll
  for (int i = 0; i < ELEMS; ++i) {
    const int idx = tid + i * T;   // coalesced: consecutive lanes -> consecutive addrs
    zr[i] = zr0[idx];
    zi[i] = zi0[idx];
    om[i] = om_in[idx];
    sr += zr[i]; si += zi[i];
  }
  float bsr, bsi;
  block_sum2(sr, si, red, bsr, bsi);
  if (threadIdx.x == 0) pbuf[blockIdx.x] = make_float2(bsr, bsi);  // buf 0
  grid.sync();

  // ---- main integration loop: 1 grid sync per step ----
  for (int s = 0; s < steps; ++s) {
    // every block redundantly reduces the 256 block-partials of buf[s&1]
    const float2* cur = pbuf + (size_t)(s & 1) * NBLK;
    float a = 0.f, b = 0.f;
    if (threadIdx.x < NBLK) { float2 p = cur[threadIdx.x]; a = p.x; b = p.y; }
    float tsr, tsi;
    block_sum2(a, b, red, tsr, tsi);
    const float mr = tsr * invN;
    const float mi = tsi * invN;

    sr = 0.f; si = 0.f;
    #pragma unroll
    for (int i = 0; i < ELEMS; ++i) {
      const float x = zr[i], y = zi[i];
      const float a2  = x * x + y * y;
      const float dzr = mu * x - om[i] * y - a2 * x + cpl * (mr - x);
      const float dzi = mu * y + om[i] * x - a2 * y + cpl * (mi - y);
      zr[i] = x + DT * dzr;
      zi[i] = y + DT * dzi;
      sr += zr[i]; si += zi[i];
    }
    block_sum2(sr, si, red, bsr, bsi);
    // write NEXT step's partials into the other buffer (no zeroing, no atomics)
    if (threadIdx.x == 0)
      pbuf[(size_t)((s + 1) & 1) * NBLK + blockIdx.x] = make_float2(bsr, bsi);
    grid.sync();
  }

  // ---- epilogue: final means, outputs, mean amplitude ----
  const float2* cur = pbuf + (size_t)(steps & 1) * NBLK;
  float a = 0.f, b = 0.f;
  if (threadIdx.x < NBLK) { float2 p = cur[threadIdx.x]; a = p.x; b = p.y; }
  float tsr, tsi;
  block_sum2(a, b, red, tsr, tsi);
  const float mr = tsr * invN;
  const float mi = tsi * invN;

  float asum = 0.f;
  #pragma unroll
  for (int i = 0; i < ELEMS; ++i) {
    const int idx = tid + i * T;
    const float x = zr[i], y = zi[i];
    const float amp = sqrtf(x * x + y * y);
    out[idx]             = amp;             // amplitudes
    out[n + idx]         = atan2f(y, x);    // phases
    out[2 * n + 1 + idx] = x;               // zr
    out[3 * n + 1 + idx] = y;               // zi
    asum += amp;
  }
  float bas, dumb;
  block_sum2(asum, 0.f, red, bas, dumb);
  if (threadIdx.x == 0) pbuf[2 * NBLK + blockIdx.x] = make_float2(bas, 0.f);
  grid.sync();

  if (blockIdx.x == 0) {
    float av = 0.f;
    if (threadIdx.x < NBLK) av = pbuf[2 * NBLK + threadIdx.x].x;
    float tot, d2;
    block_sum2(av, 0.f, red, tot, d2);
    if (threadIdx.x == 0) {
      out[2 * n]     = sqrtf(mr * mr + mi * mi);  // order_parameter
      out[4 * n + 1] = tot * invN;                // mean_amplitude
    }
  }
}

extern "C" void kernel_launch(void* const* d_in, const int* in_sizes, int n_in,
                              void* d_out, int out_size, void* d_ws, size_t ws_size,
                              hipStream_t stream) {
  const float* zr0  = (const float*)d_in[0];
  const float* zi0  = (const float*)d_in[1];
  const float* om   = (const float*)d_in[2];
  const float* mu_p = (const float*)d_in[3];
  const float* cp_p = (const float*)d_in[4];
  const int*   st_p = (const int*)d_in[5];
  float*  out  = (float*)d_out;
  float2* pbuf = (float2*)d_ws;   // 3*NBLK float2 = 6 KB
  int n = in_sizes[0];

  void* args[] = {(void*)&zr0, (void*)&zi0, (void*)&om, (void*)&mu_p,
                  (void*)&cp_p, (void*)&st_p, (void*)&out, (void*)&pbuf, (void*)&n};
  hipLaunchCooperativeKernel(reinterpret_cast<void*>(sl_persistent),
                             dim3(NBLK), dim3(NTHR), args, 0, stream);
}

// Round 4
// 319.186 us; speedup vs baseline: 3.5249x; 3.5249x over previous
//
#include <hip/hip_runtime.h>

// N = 4,194,304 = NBLK * NTHR * ELEMS exactly.
constexpr int NBLK  = 256;   // 1 block per CU
constexpr int NTHR  = 1024;  // 16 waves/block
constexpr int ELEMS = 16;    // per-thread oscillators in registers
constexpr float DT  = 0.01f;

// d_ws layout (<= 9472 B):
//   [0,    256) : unsigned cnt[64]       per-step arrival counters (memset 0)
//   [256, 8448) : float2 part[4][NBLK]   mean-free partial sums, 4-slot rotation
//   [8448,9472) : float  ampp[NBLK]      amplitude partials

// Block-wide sum of two floats, result broadcast to all threads.
// ENTRY_SYNC separates red[] writes from a previous call's readers; callers
// immediately preceded by wait_all() (which ends in __syncthreads) pass false.
template <bool ENTRY_SYNC>
__device__ inline void block_sum2(float a, float b, float* red,
                                  float& oa, float& ob) {
  #pragma unroll
  for (int off = 32; off > 0; off >>= 1) {
    a += __shfl_down(a, off);
    b += __shfl_down(b, off);
  }
  const int lane = threadIdx.x & 63;
  const int wv   = threadIdx.x >> 6;   // 0..15
  if (ENTRY_SYNC) __syncthreads();
  if (lane == 0) { red[wv] = a; red[16 + wv] = b; }
  __syncthreads();
  float sa = 0.f, sb = 0.f;
  #pragma unroll
  for (int w = 0; w < 16; ++w) { sa += red[w]; sb += red[16 + w]; }
  oa = sa; ob = sb;
}

// Publish this block's partial coherently and arrive at counter c.
// The agent-scope store's vmcnt ack == visibility at the coherent point, so
// s_waitcnt vmcnt(0) + relaxed fetch_add gives release semantics without the
// full-L2 writeback grid.sync() would do.
__device__ inline void publish2(float2* slot, float a, float b, unsigned* c) {
  if (threadIdx.x == 0) {
    union { float2 f; unsigned long long u; } v; v.f = make_float2(a, b);
    __hip_atomic_store(reinterpret_cast<unsigned long long*>(slot), v.u,
                       __ATOMIC_RELAXED, __HIP_MEMORY_SCOPE_AGENT);
    asm volatile("s_waitcnt vmcnt(0)" ::: "memory");
    __hip_atomic_fetch_add(c, 1u, __ATOMIC_RELAXED, __HIP_MEMORY_SCOPE_AGENT);
  }
}

// Wait until all NBLK blocks arrived at counter c. Thread 0 spins, block joins.
__device__ inline void wait_all(unsigned* c) {
  if (threadIdx.x == 0) {
    while (__hip_atomic_load(c, __ATOMIC_RELAXED, __HIP_MEMORY_SCOPE_AGENT)
           < (unsigned)NBLK)
      __builtin_amdgcn_s_sleep(1);
  }
  __syncthreads();
}

__device__ inline float2 load2(float2* slot) {
  union { float2 f; unsigned long long u; } v;
  v.u = __hip_atomic_load(reinterpret_cast<unsigned long long*>(slot),
                          __ATOMIC_RELAXED, __HIP_MEMORY_SCOPE_AGENT);
  return v.f;
}

// Pipeline: registers hold u_s (mean-free state), z_s = u_s + dt*c*m_{s-1}.
//   u_{s+1} = z_s + dt*(f_local(z_s) - c*z_s)        [no mean needed]
//   m_s     = (Sum u_s)/N + dt*c*m_{s-1}             [linear recursion]
// Each iteration publishes Sum(u_{s+1}) BEFORE waiting on Sum(u_s), so the
// barrier for step s resolves while the step-s heavy loop runs elsewhere.
__global__ __launch_bounds__(NTHR, 4)
void sl_persistent(const float* __restrict__ zr0,
                   const float* __restrict__ zi0,
                   const float* __restrict__ om_in,
                   const float* __restrict__ mu_p,
                   const float* __restrict__ cp_p,
                   const int*   __restrict__ st_p,
                   float* __restrict__ out,
                   void* __restrict__ ws,
                   int n) {
  __shared__ float red[32];
  unsigned* cnt = reinterpret_cast<unsigned*>(ws);
  float2*  part = reinterpret_cast<float2*>((char*)ws + 256);
  float*   ampp = reinterpret_cast<float*>((char*)ws + 8448);

  const int tid = blockIdx.x * NTHR + threadIdx.x;
  const int T   = NBLK * NTHR;
  const float mu    = *mu_p;
  const float cpl   = *cp_p;
  const int   steps = *st_p;
  const float invN  = 1.0f / (float)n;
  const float dtc   = DT * cpl;
  const float muc   = mu - cpl;

  // ---- load state (u_0 = z_0, m_{-1} = 0), publish Sum(u_0) ----
  float ur[ELEMS], ui[ELEMS], om[ELEMS];
  float sr = 0.f, si = 0.f;
  #pragma unroll
  for (int i = 0; i < ELEMS; ++i) {
    const int idx = tid + i * T;   // coalesced
    ur[i] = zr0[idx];
    ui[i] = zi0[idx];
    om[i] = om_in[idx];
    sr += ur[i]; si += ui[i];
  }
  float bsr, bsi;
  block_sum2<false>(sr, si, red, bsr, bsi);
  publish2(&part[0 * NBLK + blockIdx.x], bsr, bsi, &cnt[0]);

  float mr = 0.f, mi = 0.f;   // m_{s-1}, starts as m_{-1} = 0

  // ---- main loop ----
  for (int s = 0; s < steps; ++s) {
    // fixup to z_s with m_{s-1}, heavy local step to u_{s+1}, block partial
    sr = 0.f; si = 0.f;
    #pragma unroll
    for (int i = 0; i < ELEMS; ++i) {
      const float x  = fmaf(dtc, mr, ur[i]);     // z_s
      const float y  = fmaf(dtc, mi, ui[i]);
      const float a2 = fmaf(x, x, y * y);
      const float g  = muc - a2;                 // (mu - c) - |z|^2
      const float dr = fmaf(g, x, -om[i] * y);
      const float di = fmaf(g, y,  om[i] * x);
      ur[i] = fmaf(DT, dr, x);                   // u_{s+1}
      ui[i] = fmaf(DT, di, y);
      sr += ur[i]; si += ui[i];
    }
    block_sum2<true>(sr, si, red, bsr, bsi);
    publish2(&part[((s + 1) & 3) * NBLK + blockIdx.x], bsr, bsi, &cnt[s + 1]);

    // resolve m_s from Sum(u_s) — published one heavy-loop ago, so the
    // barrier latency is already (mostly) paid
    wait_all(&cnt[s]);
    float a = 0.f, b = 0.f;
    if (threadIdx.x < NBLK) {
      float2 p = load2(&part[(s & 3) * NBLK + threadIdx.x]);
      a = p.x; b = p.y;
    }
    float tsr, tsi;
    block_sum2<false>(a, b, red, tsr, tsi);
    mr = fmaf(dtc, mr, tsr * invN);   // m_s
    mi = fmaf(dtc, mi, tsi * invN);
  }

  // ---- epilogue: z_final = u_steps + dt*c*m_{steps-1} ----
  float asum = 0.f;
  #pragma unroll
  for (int i = 0; i < ELEMS; ++i) {
    const int idx = tid + i * T;
    const float x = fmaf(dtc, mr, ur[i]);
    const float y = fmaf(dtc, mi, ui[i]);
    const float amp = sqrtf(fmaf(x, x, y * y));
    out[idx]             = amp;             // amplitudes
    out[n + idx]         = atan2f(y, x);    // phases
    out[2 * n + 1 + idx] = x;               // zr
    out[3 * n + 1 + idx] = y;               // zi
    asum += amp;
  }
  float bas, dummy;
  block_sum2<true>(asum, 0.f, red, bas, dummy);
  if (threadIdx.x == 0) {
    __hip_atomic_store(&ampp[blockIdx.x], bas,
                       __ATOMIC_RELAXED, __HIP_MEMORY_SCOPE_AGENT);
    asm volatile("s_waitcnt vmcnt(0)" ::: "memory");
    __hip_atomic_fetch_add(&cnt[steps + 1], 1u,
                           __ATOMIC_RELAXED, __HIP_MEMORY_SCOPE_AGENT);
  }

  if (blockIdx.x == 0) {
    // m_steps for order_parameter
    wait_all(&cnt[steps]);
    float a = 0.f, b = 0.f;
    if (threadIdx.x < NBLK) {
      float2 p = load2(&part[(steps & 3) * NBLK + threadIdx.x]);
      a = p.x; b = p.y;
    }
    float tsr, tsi;
    block_sum2<false>(a, b, red, tsr, tsi);
    const float fmr = fmaf(dtc, mr, tsr * invN);
    const float fmi = fmaf(dtc, mi, tsi * invN);

    wait_all(&cnt[steps + 1]);
    float av = 0.f;
    if (threadIdx.x < NBLK)
      av = __hip_atomic_load(&ampp[threadIdx.x],
                             __ATOMIC_RELAXED, __HIP_MEMORY_SCOPE_AGENT);
    float tot, d2;
    block_sum2<false>(av, 0.f, red, tot, d2);
    if (threadIdx.x == 0) {
      out[2 * n]     = sqrtf(fmaf(fmr, fmr, fmi * fmi));  // order_parameter
      out[4 * n + 1] = tot * invN;                        // mean_amplitude
    }
  }
}

extern "C" void kernel_launch(void* const* d_in, const int* in_sizes, int n_in,
                              void* d_out, int out_size, void* d_ws, size_t ws_size,
                              hipStream_t stream) {
  const float* zr0  = (const float*)d_in[0];
  const float* zi0  = (const float*)d_in[1];
  const float* om   = (const float*)d_in[2];
  const float* mu_p = (const float*)d_in[3];
  const float* cp_p = (const float*)d_in[4];
  const int*   st_p = (const int*)d_in[5];
  float* out = (float*)d_out;
  int n = in_sizes[0];

  // zero the arrival counters (d_ws is re-poisoned to 0xAA before every launch)
  hipMemsetAsync(d_ws, 0, 256, stream);

  void* args[] = {(void*)&zr0, (void*)&zi0, (void*)&om, (void*)&mu_p,
                  (void*)&cp_p, (void*)&st_p, (void*)&out, (void*)&d_ws, (void*)&n};
  hipLaunchCooperativeKernel(reinterpret_cast<void*>(sl_persistent),
                             dim3(NBLK), dim3(NTHR), args, 0, stream);
}

// Round 7
// 236.974 us; speedup vs baseline: 4.7478x; 1.3469x over previous
//
#include <hip/hip_runtime.h>

// N = 4,194,304 = NBLK * NTHR * ELEMS exactly.
constexpr int NBLK  = 256;   // 1 block per CU
constexpr int NTHR  = 1024;  // 16 waves/block
constexpr int ELEMS = 16;    // per-thread oscillators in registers
constexpr float DT  = 0.01f;
constexpr int DEPTH = 8;     // slot rotation depth (>=4 provably ABA-safe)

// d_ws layout (35 KB, memset to 0 each launch -> tag 0 matches nothing):
//   [0, 32768)      : Slot part[DEPTH][NBLK]   tagged mean-free partials
//   [32768, 34816)  : u64  ampp[NBLK]          tagged amplitude partials
// Slot word: hi32 = tag (= step_index+1, or steps+2 for amp), lo32 = f32 bits.
// Single writer per word per launch-phase; relaxed 8B atomics are inherently
// untearable, so publishing needs NO fences, NO vmcnt, NO RMW counters.
struct Slot { unsigned long long a, b; };

__device__ inline unsigned long long pack(unsigned tag, float x) {
  return ((unsigned long long)tag << 32) |
         (unsigned long long)__float_as_uint(x);
}
__device__ inline void st8(unsigned long long* p, unsigned long long v) {
  __hip_atomic_store(p, v, __ATOMIC_RELAXED, __HIP_MEMORY_SCOPE_AGENT);
}
__device__ inline float poll_payload(unsigned long long* p, unsigned tag) {
  unsigned long long v = __hip_atomic_load(p, __ATOMIC_RELAXED,
                                           __HIP_MEMORY_SCOPE_AGENT);
  while ((unsigned)(v >> 32) != tag) {
    __builtin_amdgcn_s_sleep(1);
    v = __hip_atomic_load(p, __ATOMIC_RELAXED, __HIP_MEMORY_SCOPE_AGENT);
  }
  return __uint_as_float((unsigned)v);
}

// Block-wide sum of two floats, result broadcast to all threads.
// ENTRY_SYNC=true protects red[] from the previous call's readers.
template <bool ENTRY_SYNC>
__device__ inline void block_sum2(float a, float b, float* red,
                                  float& oa, float& ob) {
  #pragma unroll
  for (int off = 32; off > 0; off >>= 1) {
    a += __shfl_down(a, off);
    b += __shfl_down(b, off);
  }
  const int lane = threadIdx.x & 63;
  const int wv   = threadIdx.x >> 6;   // 0..15
  if (ENTRY_SYNC) __syncthreads();
  if (lane == 0) { red[wv] = a; red[16 + wv] = b; }
  __syncthreads();
  float sa = 0.f, sb = 0.f;
  #pragma unroll
  for (int w = 0; w < 16; ++w) { sa += red[w]; sb += red[16 + w]; }
  oa = sa; ob = sb;
}

// Pipeline: registers hold u_s (mean-free state), z_s = u_s + dt*c*m_{s-1}.
//   u_{s+1} = z_s + dt*(f_local(z_s) - c*z_s)        [no mean needed]
//   m_s     = (Sum u_s)/N + dt*c*m_{s-1}             [linear recursion]
// Each iteration publishes Sum(u_{s+1}) BEFORE polling Sum(u_s), so the
// straggler's store-visibility latency overlaps the next heavy loop.
__global__ __launch_bounds__(NTHR, 4)
void sl_persistent(const float* __restrict__ zr0,
                   const float* __restrict__ zi0,
                   const float* __restrict__ om_in,
                   const float* __restrict__ mu_p,
                   const float* __restrict__ cp_p,
                   const int*   __restrict__ st_p,
                   float* __restrict__ out,
                   void* __restrict__ ws,
                   int n) {
  __shared__ float red[32];
  Slot* part = reinterpret_cast<Slot*>(ws);
  unsigned long long* ampp =
      reinterpret_cast<unsigned long long*>((char*)ws + DEPTH * NBLK * 16);

  const int tid = blockIdx.x * NTHR + threadIdx.x;
  const int T   = NBLK * NTHR;
  const float mu    = *mu_p;
  const float cpl   = *cp_p;
  const int   steps = *st_p;
  const float invN  = 1.0f / (float)n;
  const float dtc   = DT * cpl;
  const float muc   = mu - cpl;

  // ---- load state (u_0 = z_0, m_{-1} = 0), publish Sum(u_0) as slot 0 ----
  float ur[ELEMS], ui[ELEMS], om[ELEMS];
  float sr = 0.f, si = 0.f;
  #pragma unroll
  for (int i = 0; i < ELEMS; ++i) {
    const int idx = tid + i * T;   // coalesced
    ur[i] = zr0[idx];
    ui[i] = zi0[idx];
    om[i] = om_in[idx];
    sr += ur[i]; si += ui[i];
  }
  float bsr, bsi;
  block_sum2<false>(sr, si, red, bsr, bsi);
  if (threadIdx.x == 0) {
    Slot* sl = &part[0 * NBLK + blockIdx.x];
    st8(&sl->a, pack(1u, bsr));
    st8(&sl->b, pack(1u, bsi));
  }

  float mr = 0.f, mi = 0.f;   // m_{s-1}, starts as m_{-1} = 0

  // ---- main loop: tagged-slot barrier, no RMW, no hot line ----
  for (int s = 0; s < steps; ++s) {
    // fixup to z_s with m_{s-1}, heavy local step to u_{s+1}, block partial
    sr = 0.f; si = 0.f;
    #pragma unroll
    for (int i = 0; i < ELEMS; ++i) {
      const float x  = fmaf(dtc, mr, ur[i]);     // z_s
      const float y  = fmaf(dtc, mi, ui[i]);
      const float a2 = fmaf(x, x, y * y);
      const float g  = muc - a2;                 // (mu - c) - |z|^2
      const float dr = fmaf(g, x, -om[i] * y);
      const float di = fmaf(g, y,  om[i] * x);
      ur[i] = fmaf(DT, dr, x);                   // u_{s+1}
      ui[i] = fmaf(DT, di, y);
      sr += ur[i]; si += ui[i];
    }
    block_sum2<true>(sr, si, red, bsr, bsi);
    if (threadIdx.x == 0) {                      // publish slot s+1
      Slot* sl = &part[((s + 1) & (DEPTH - 1)) * NBLK + blockIdx.x];
      st8(&sl->a, pack((unsigned)(s + 2), bsr));
      st8(&sl->b, pack((unsigned)(s + 2), bsi));
    }

    // poll slot s (published one heavy-loop ago), reduce, advance m
    float a = 0.f, b = 0.f;
    if (threadIdx.x < NBLK) {
      Slot* sl = &part[(s & (DEPTH - 1)) * NBLK + threadIdx.x];
      a = poll_payload(&sl->a, (unsigned)(s + 1));
      b = poll_payload(&sl->b, (unsigned)(s + 1));
    }
    float tsr, tsi;
    block_sum2<true>(a, b, red, tsr, tsi);
    mr = fmaf(dtc, mr, tsr * invN);   // m_s
    mi = fmaf(dtc, mi, tsi * invN);
  }

  // ---- epilogue: z_final = u_steps + dt*c*m_{steps-1} ----
  float asum = 0.f;
  #pragma unroll
  for (int i = 0; i < ELEMS; ++i) {
    const int idx = tid + i * T;
    const float x = fmaf(dtc, mr, ur[i]);
    const float y = fmaf(dtc, mi, ui[i]);
    const float amp = sqrtf(fmaf(x, x, y * y));
    out[idx]             = amp;             // amplitudes
    out[n + idx]         = atan2f(y, x);    // phases
    out[2 * n + 1 + idx] = x;               // zr
    out[3 * n + 1 + idx] = y;               // zi
    asum += amp;
  }
  float bas, dummy;
  block_sum2<true>(asum, 0.f, red, bas, dummy);
  if (threadIdx.x == 0)
    st8(&ampp[blockIdx.x], pack((unsigned)(steps + 2), bas));

  if (blockIdx.x == 0) {
    // m_steps for order_parameter (slot `steps` published in last iteration)
    float a = 0.f, b = 0.f;
    if (threadIdx.x < NBLK) {
      Slot* sl = &part[(steps & (DEPTH - 1)) * NBLK + threadIdx.x];
      a = poll_payload(&sl->a, (unsigned)(steps + 1));
      b = poll_payload(&sl->b, (unsigned)(steps + 1));
    }
    float tsr, tsi;
    block_sum2<true>(a, b, red, tsr, tsi);
    const float fmr = fmaf(dtc, mr, tsr * invN);
    const float fmi = fmaf(dtc, mi, tsi * invN);

    float av = 0.f;
    if (threadIdx.x < NBLK)
      av = poll_payload(&ampp[threadIdx.x], (unsigned)(steps + 2));
    float tot, d2;
    block_sum2<true>(av, 0.f, red, tot, d2);
    if (threadIdx.x == 0) {
      out[2 * n]     = sqrtf(fmaf(fmr, fmr, fmi * fmi));  // order_parameter
      out[4 * n + 1] = tot * invN;                        // mean_amplitude
    }
  }
}

extern "C" void kernel_launch(void* const* d_in, const int* in_sizes, int n_in,
                              void* d_out, int out_size, void* d_ws, size_t ws_size,
                              hipStream_t stream) {
  const float* zr0  = (const float*)d_in[0];
  const float* zi0  = (const float*)d_in[1];
  const float* om   = (const float*)d_in[2];
  const float* mu_p = (const float*)d_in[3];
  const float* cp_p = (const float*)d_in[4];
  const int*   st_p = (const int*)d_in[5];
  float* out = (float*)d_out;
  int n = in_sizes[0];

  // zero the tag region (tag 0 never matches; d_ws is re-poisoned to 0xAA
  // before every timed launch, and 0xAAAAAAAA never matches a tag either —
  // the memset just makes the correctness call deterministic too)
  hipMemsetAsync(d_ws, 0, DEPTH * NBLK * 16 + NBLK * 8, stream);

  void* args[] = {(void*)&zr0, (void*)&zi0, (void*)&om, (void*)&mu_p,
                  (void*)&cp_p, (void*)&st_p, (void*)&out, (void*)&d_ws, (void*)&n};
  hipLaunchCooperativeKernel(reinterpret_cast<void*>(sl_persistent),
                             dim3(NBLK), dim3(NTHR), args, 0, stream);
}